// Round 2
// baseline (1125.231 us; speedup 1.0000x reference)
//
#include <hip/hip_runtime.h>

#define EPS_LN 1e-4f

// ---------------------------------------------------------------------------
// Kernel 1: gather -> (1x32)@(32x64) -> scatter-add.
// One wave (64 lanes) per rule; lane == output channel (COUT == 64).
// W[k][c][lane] preloaded into 32 VGPRs (k fixed per block via blockIdx.y).
// feats row broadcast across the wave with __shfl.
// ---------------------------------------------------------------------------
__global__ __launch_bounds__(256) void scatter_conv_kernel(
    const float* __restrict__ feats,
    const float* __restrict__ W,
    const int* __restrict__ gidx,
    const int* __restrict__ sidx,
    float* __restrict__ out,
    int P, int n_out) {
  const int lane = threadIdx.x & 63;
  const int k = blockIdx.y;
  const int wavesPerBlock = blockDim.x >> 6;
  const int wave = blockIdx.x * wavesPerBlock + (threadIdx.x >> 6);
  const int waveStride = gridDim.x * wavesPerBlock;

  // W[k] column for my output channel: 32 registers.
  float w[32];
#pragma unroll
  for (int c = 0; c < 32; ++c) w[c] = W[((k * 32 + c) << 6) + lane];

  const int base = k * P;
  for (int p = wave; p < P; p += waveStride) {
    const int g = gidx[base + p];   // uniform across wave -> broadcast load
    const int s = sidx[base + p];
    // lanes 0..31 hold the 32 feats values; lanes 32..63 duplicate (same line)
    const float f = feats[(long)g * 32 + (lane & 31)];
    float acc = 0.f;
#pragma unroll
    for (int c = 0; c < 32; ++c) acc += __shfl(f, c) * w[c];
    if (s < n_out) {  // s == n_out is the rulebook's padding dump row
      atomicAdd(out + ((long)s << 6) + lane, acc);  // 64 lanes = 256B contiguous
    }
  }
}

// ---------------------------------------------------------------------------
// Kernel 2: per-channel sum / sumsq over the accumulated conv output.
// float4 grid-stride; each thread's 4 channels are fixed (stride % 64 == 0).
// ---------------------------------------------------------------------------
__global__ __launch_bounds__(256) void stats_kernel(
    const float4* __restrict__ out, float* __restrict__ ws, long total4) {
  const long stride = (long)gridDim.x * blockDim.x;
  float s1[4] = {0.f, 0.f, 0.f, 0.f};
  float s2[4] = {0.f, 0.f, 0.f, 0.f};
  for (long i = (long)blockIdx.x * blockDim.x + threadIdx.x; i < total4; i += stride) {
    float4 x = out[i];
    s1[0] += x.x; s2[0] += x.x * x.x;
    s1[1] += x.y; s2[1] += x.y * x.y;
    s1[2] += x.z; s2[2] += x.z * x.z;
    s1[3] += x.w; s2[3] += x.w * x.w;
  }
  __shared__ float ls[128];
  if (threadIdx.x < 128) ls[threadIdx.x] = 0.f;
  __syncthreads();
  const int cb = (threadIdx.x << 2) & 63;  // my channel base
#pragma unroll
  for (int j = 0; j < 4; ++j) {
    atomicAdd(&ls[cb + j], s1[j]);
    atomicAdd(&ls[64 + cb + j], s2[j]);
  }
  __syncthreads();
  if (threadIdx.x < 128) atomicAdd(&ws[threadIdx.x], ls[threadIdx.x]);
}

// ---------------------------------------------------------------------------
// Kernel 3: fold sums into per-channel scale/shift (one tiny block).
// ---------------------------------------------------------------------------
__global__ void finalize_stats_kernel(float* __restrict__ ws,
                                      const float* __restrict__ gamma,
                                      const float* __restrict__ beta,
                                      float inv_n) {
  const int c = threadIdx.x;  // 64 threads
  const float mean = ws[c] * inv_n;
  const float var = ws[64 + c] * inv_n - mean * mean;
  const float sc = rsqrtf(var + EPS_LN) * gamma[c];
  ws[128 + c] = sc;
  ws[192 + c] = beta[c] - mean * sc;
}

// ---------------------------------------------------------------------------
// Kernel 4: in-place normalize + ReLU, float4.
// ---------------------------------------------------------------------------
__global__ __launch_bounds__(256) void normalize_kernel(
    float4* __restrict__ out, const float* __restrict__ ws, long total4) {
  const long stride = (long)gridDim.x * blockDim.x;
  const int cb = (threadIdx.x << 2) & 63;  // fixed channel base per thread
  const float4 sc = *(const float4*)(ws + 128 + cb);
  const float4 sh = *(const float4*)(ws + 192 + cb);
  for (long i = (long)blockIdx.x * blockDim.x + threadIdx.x; i < total4; i += stride) {
    float4 x = out[i];
    x.x = fmaxf(fmaf(x.x, sc.x, sh.x), 0.f);
    x.y = fmaxf(fmaf(x.y, sc.y, sh.y), 0.f);
    x.z = fmaxf(fmaf(x.z, sc.z, sh.z), 0.f);
    x.w = fmaxf(fmaf(x.w, sc.w, sh.w), 0.f);
    out[i] = x;
  }
}

extern "C" void kernel_launch(void* const* d_in, const int* in_sizes, int n_in,
                              void* d_out, int out_size, void* d_ws, size_t ws_size,
                              hipStream_t stream) {
  const float* feats = (const float*)d_in[0];
  const float* W     = (const float*)d_in[1];
  const float* gamma = (const float*)d_in[2];
  const float* beta  = (const float*)d_in[3];
  const int*   gidx  = (const int*)d_in[4];
  const int*   sidx  = (const int*)d_in[5];

  const int P = in_sizes[4] / 4;       // KVOL == 4
  const int n_out = out_size / 64;     // COUT == 64
  float* out = (float*)d_out;
  float* ws  = (float*)d_ws;

  // d_out is NOT re-poisoned between replays: zero it every call.
  hipMemsetAsync(d_out, 0, (size_t)out_size * sizeof(float), stream);
  hipMemsetAsync(d_ws, 0, 256 * sizeof(float), stream);

  dim3 sgrid(2048, 4);
  scatter_conv_kernel<<<sgrid, 256, 0, stream>>>(feats, W, gidx, sidx, out, P, n_out);

  const long total4 = (long)out_size / 4;
  stats_kernel<<<2048, 256, 0, stream>>>((const float4*)out, ws, total4);
  finalize_stats_kernel<<<1, 64, 0, stream>>>(ws, gamma, beta, 1.0f / (float)n_out);
  normalize_kernel<<<2048, 256, 0, stream>>>((float4*)out, ws, total4);
}